// Round 9
// baseline (1299.258 us; speedup 1.0000x reference)
//
#include <hip/hip_runtime.h>
#include <math.h>

// ---------------------------------------------------------------------------
// Com_CNN_RNN R14 (base = R13, best measured 1271.9us):
//  Memory-side ATOMIC pub/probe - the one sync family not yet tested.
//  - publish: __hip_atomic_exchange (RMW executes AT the MALL atomic unit ->
//    committed+globally visible at execution; no write-buffer/L2 laziness).
//  - probe:   __hip_atomic_fetch_or(p, 0) (forced MALL round trip; immune to
//    any cache staleness on the consumer side).
//  - heater removed (R13: VALUBusy 8.5->11.4% proved FMAs ran, period
//    unchanged -> DPM theory dead; keep loops clean, single variable).
//  Everything else = R13: gi GEMM folded into k_pipe L0 (wi registers),
//  packed 8B publishes, canary = FLT_MAX bits (|GRU h| < 1), k_tail with
//  replicated conv, k_init re-poisons every launch (graph-replay safe).
// ---------------------------------------------------------------------------

#define CANARY_U 0x7F7FFFFFu
#define SPIN_HOT 1024   // probes before s_sleep backoff (contention hedge)

__device__ __forceinline__ float sigm(float x) { return 1.f / (1.f + expf(-x)); }

// LDS index map: p(k) = k + (k>>4)*4 (pad 4 words per 16; keeps float4 align)
#define LDSP(k) ((k) + (((k) >> 4) << 2))

__device__ __forceinline__ float red32(float v) {
    v += __shfl_xor(v, 16, 64);
    v += __shfl_xor(v, 8, 64);
    v += __shfl_xor(v, 4, 64);
    v += __shfl_xor(v, 2, 64);
    v += __shfl_xor(v, 1, 64);
    return v;
}

// Publisher: half-wave lane0 packs h for both sentences of row j into 8B,
// committed at the coherence point via atomic exchange.
__device__ __forceinline__ void pub2(float* base, int j, float h0, float h1) {
    union { float2 f; unsigned long long u; } p;
    p.f = make_float2(h0, h1);
    (void)__hip_atomic_exchange((unsigned long long*)base + j, p.u,
                                __ATOMIC_RELAXED, __HIP_MEMORY_SCOPE_AGENT);
}

// Probe one 8B word via fetch_or(0): forced MALL RMW, returns current value.
__device__ __forceinline__ unsigned long long probe8(const float* src, int w) {
    unsigned long long* p = (unsigned long long*)const_cast<float*>(src) + w;
    return __hip_atomic_fetch_or(p, 0ull, __ATOMIC_RELAXED,
                                 __HIP_MEMORY_SCOPE_AGENT);
}

// Poll ONE row (8B: both sentences) of src [512][2]; thread i covers row i.
__device__ __forceinline__ void stage_poll8(float* dst, const float* src, int i) {
    unsigned long long a;
    int it = 0;
    for (;;) {
        a = probe8(src, i);
        if ((unsigned int)a != CANARY_U && (unsigned int)(a >> 32) != CANARY_U)
            break;
        if (++it > SPIN_HOT) __builtin_amdgcn_s_sleep(1);
    }
    union { unsigned long long u; float2 f; } c; c.u = a;
    dst[LDSP(i)]       = c.f.x;      // sent0 row i
    dst[LDSP(512 + i)] = c.f.y;      // sent1 row i
}

// Poll TWO rows (16B) of src [512][2]; thread i covers rows 2i, 2i+1.
__device__ __forceinline__ void stage_pollx2(float* dst, const float* src, int i) {
    unsigned long long a, b;
    int it = 0;
    for (;;) {
        a = probe8(src, 2 * i);
        b = probe8(src, 2 * i + 1);
        if ((unsigned int)a != CANARY_U && (unsigned int)(a >> 32) != CANARY_U &&
            (unsigned int)b != CANARY_U && (unsigned int)(b >> 32) != CANARY_U)
            break;
        if (++it > SPIN_HOT) __builtin_amdgcn_s_sleep(1);
    }
    union { unsigned long long u; float2 f; } c0, c1;
    c0.u = a; c1.u = b;
    const int r0 = 2 * i, r1 = 2 * i + 1;
    dst[LDSP(r0)]       = c0.f.x;
    dst[LDSP(512 + r0)] = c0.f.y;
    dst[LDSP(r1)]       = c1.f.x;
    dst[LDSP(512 + r1)] = c1.f.y;
}

__device__ __forceinline__ float gru1(float gr, float gz, float gn,
                                      float ar, float az, float an,
                                      const float bh[3], float hp) {
    float r = sigm(gr + ar + bh[0]);
    float z = sigm(gz + az + bh[1]);
    float n = tanhf(gn + r * (an + bh[2]));
    return (1.f - z) * n + z * hp;
}

// ---------------------------------------------------------------------------
// k_pipe: epoch-1 L0 + L1 pipelined, gi computed in-kernel. grid 64 x 512.
// hbuf layout: [257 steps][512 rows][2 sentences]
// ---------------------------------------------------------------------------
__global__ __launch_bounds__(512, 1) void k_pipe(
    const float* __restrict__ Whh1, const float* __restrict__ bhh1,
    const float* __restrict__ Wih1, const float* __restrict__ bih1,
    const float* __restrict__ emb,
    const int* __restrict__ sentA, const int* __restrict__ sentB,
    float* __restrict__ e2x,              // [2 sent][2 layer][512]
    float* __restrict__ hbuf0,            // poisoned t=1..256
    float* __restrict__ hbuf1)            // poisoned t=1..256
{
    const int tid   = threadIdx.x;
    const int layer = blockIdx.x >> 5;    // 0 or 1
    const int wgi   = blockIdx.x & 31;
    const int grp   = tid >> 5;           // 0..15 (32-lane half-wave groups)
    const int lane  = tid & 31;
    const int j     = wgi * 16 + grp;     // h row 0..511
    const int colbase = lane * 16;

    __shared__ float xlds[2][1280];
    __shared__ float hlds[2][1280];

    const size_t WS = (size_t)1536 * 512;
    const float* WH = Whh1 + (size_t)layer * WS;
    const float* WI = Wih1 + (size_t)layer * WS;

    // recurrent + input weights register-resident (48 + 48 floats)
    float wh[3][16], wi[3][16];
#pragma unroll
    for (int q = 0; q < 3; ++q) {
        const float* srch = WH + (size_t)(q * 512 + j) * 512 + colbase;
        const float* srci = WI + (size_t)(q * 512 + j) * 512 + colbase;
#pragma unroll
        for (int c4 = 0; c4 < 4; ++c4) {
            float4 v = *(const float4*)(srch + c4 * 4);
            wh[q][c4*4+0] = v.x; wh[q][c4*4+1] = v.y;
            wh[q][c4*4+2] = v.z; wh[q][c4*4+3] = v.w;
            float4 w = *(const float4*)(srci + c4 * 4);
            wi[q][c4*4+0] = w.x; wi[q][c4*4+1] = w.y;
            wi[q][c4*4+2] = w.z; wi[q][c4*4+3] = w.w;
        }
    }
#pragma unroll
    for (int q = 0; q < 3; ++q)
#pragma unroll
        for (int c = 0; c < 16; ++c) {
            asm volatile("" : "+v"(wh[q][c]));
            asm volatile("" : "+v"(wi[q][c]));
        }

    float bh[3], bi[3];
#pragma unroll
    for (int q = 0; q < 3; ++q) {
        bh[q] = bhh1[layer * 1536 + q * 512 + j];
        bi[q] = bih1[layer * 1536 + q * 512 + j];
    }

    float hprev[2] = {0.f, 0.f};
    int buf = 0;

    if (layer == 0) {
        // ---------------- L0: x = emb[sent[t-1]], gi computed in-kernel ------
        for (int t = 1; t <= 256; ++t) {
            // issue x loads before the poll (latency overlaps poll wait)
            const int ta = sentA[t - 1], tb = sentB[t - 1];
            const float* xa = emb + (size_t)ta * 512 + colbase;
            const float* xb = emb + (size_t)tb * 512 + colbase;
            float4 xav[4], xbv[4];
#pragma unroll
            for (int c4 = 0; c4 < 4; ++c4) {
                xav[c4] = *(const float4*)(xa + c4 * 4);
                xbv[c4] = *(const float4*)(xb + c4 * 4);
            }

            if (t > 1) {
                stage_poll8(xlds[buf], hbuf0 + (size_t)(t - 1) * 1024, tid);
                __syncthreads();
            }

            float aR[2] = {0.f,0.f}, aZ[2] = {0.f,0.f};
            float aGN[2] = {0.f,0.f}, aHN[2] = {0.f,0.f};
#pragma unroll
            for (int s = 0; s < 2; ++s) {
                const float4* xv = s ? xbv : xav;
#pragma unroll
                for (int c4 = 0; c4 < 4; ++c4) {
                    const float4 v = xv[c4];
                    aR[s]  += wi[0][c4*4+0]*v.x + wi[0][c4*4+1]*v.y
                            + wi[0][c4*4+2]*v.z + wi[0][c4*4+3]*v.w;
                    aZ[s]  += wi[1][c4*4+0]*v.x + wi[1][c4*4+1]*v.y
                            + wi[1][c4*4+2]*v.z + wi[1][c4*4+3]*v.w;
                    aGN[s] += wi[2][c4*4+0]*v.x + wi[2][c4*4+1]*v.y
                            + wi[2][c4*4+2]*v.z + wi[2][c4*4+3]*v.w;
                }
                if (t > 1) {
                    const int base = s * 640 + 20 * lane;
#pragma unroll
                    for (int c4 = 0; c4 < 4; ++c4) {
                        float4 hv = *(const float4*)&xlds[buf][base + c4 * 4];
                        aR[s]  += wh[0][c4*4+0]*hv.x + wh[0][c4*4+1]*hv.y
                                + wh[0][c4*4+2]*hv.z + wh[0][c4*4+3]*hv.w;
                        aZ[s]  += wh[1][c4*4+0]*hv.x + wh[1][c4*4+1]*hv.y
                                + wh[1][c4*4+2]*hv.z + wh[1][c4*4+3]*hv.w;
                        aHN[s] += wh[2][c4*4+0]*hv.x + wh[2][c4*4+1]*hv.y
                                + wh[2][c4*4+2]*hv.z + wh[2][c4*4+3]*hv.w;
                    }
                }
            }
#pragma unroll
            for (int s = 0; s < 2; ++s) {
                aR[s] = red32(aR[s]); aZ[s] = red32(aZ[s]);
                aGN[s] = red32(aGN[s]); aHN[s] = red32(aHN[s]);
            }

            float hn[2];
#pragma unroll
            for (int s = 0; s < 2; ++s) {
                float r = sigm(aR[s] + bi[0] + bh[0]);
                float z = sigm(aZ[s] + bi[1] + bh[1]);
                float n = tanhf(aGN[s] + bi[2] + r * (aHN[s] + bh[2]));
                hn[s] = (1.f - z) * n + z * hprev[s];
                hprev[s] = hn[s];
            }
            if (lane == 0) {
                pub2(hbuf0 + (size_t)t * 1024, j, hn[0], hn[1]);
                if (t == 256)
#pragma unroll
                    for (int s = 0; s < 2; ++s) e2x[s * 1024 + j] = hn[s];
            }
            buf ^= 1;
        }
    } else {
        // ---------------- L1 (skewed by 1 step): x = h0[t] -------------------
        for (int t = 1; t <= 256; ++t) {
            if (tid < 256)
                stage_pollx2(xlds[buf], hbuf0 + (size_t)t * 1024, tid);
            else if (t > 1)
                stage_pollx2(hlds[buf], hbuf1 + (size_t)(t - 1) * 1024, tid - 256);
            __syncthreads();

            float aR[2] = {0.f,0.f}, aZ[2] = {0.f,0.f};
            float aGN[2] = {0.f,0.f}, aHN[2] = {0.f,0.f};
#pragma unroll
            for (int s = 0; s < 2; ++s) {
                const int base = s * 640 + 20 * lane;
#pragma unroll
                for (int c4 = 0; c4 < 4; ++c4) {
                    float4 xv = *(const float4*)&xlds[buf][base + c4 * 4];
                    aR[s]  += wi[0][c4*4+0]*xv.x + wi[0][c4*4+1]*xv.y
                            + wi[0][c4*4+2]*xv.z + wi[0][c4*4+3]*xv.w;
                    aZ[s]  += wi[1][c4*4+0]*xv.x + wi[1][c4*4+1]*xv.y
                            + wi[1][c4*4+2]*xv.z + wi[1][c4*4+3]*xv.w;
                    aGN[s] += wi[2][c4*4+0]*xv.x + wi[2][c4*4+1]*xv.y
                            + wi[2][c4*4+2]*xv.z + wi[2][c4*4+3]*xv.w;
                }
                if (t > 1) {
#pragma unroll
                    for (int c4 = 0; c4 < 4; ++c4) {
                        float4 hv = *(const float4*)&hlds[buf][base + c4 * 4];
                        aR[s]  += wh[0][c4*4+0]*hv.x + wh[0][c4*4+1]*hv.y
                                + wh[0][c4*4+2]*hv.z + wh[0][c4*4+3]*hv.w;
                        aZ[s]  += wh[1][c4*4+0]*hv.x + wh[1][c4*4+1]*hv.y
                                + wh[1][c4*4+2]*hv.z + wh[1][c4*4+3]*hv.w;
                        aHN[s] += wh[2][c4*4+0]*hv.x + wh[2][c4*4+1]*hv.y
                                + wh[2][c4*4+2]*hv.z + wh[2][c4*4+3]*hv.w;
                    }
                }
            }
#pragma unroll
            for (int s = 0; s < 2; ++s) {
                aR[s] = red32(aR[s]); aZ[s] = red32(aZ[s]);
                aGN[s] = red32(aGN[s]); aHN[s] = red32(aHN[s]);
            }

            float hn[2];
#pragma unroll
            for (int s = 0; s < 2; ++s) {
                float r = sigm(aR[s] + bi[0] + bh[0]);
                float z = sigm(aZ[s] + bi[1] + bh[1]);
                float n = tanhf(aGN[s] + bi[2] + r * (aHN[s] + bh[2]));
                hn[s] = (1.f - z) * n + z * hprev[s];
                hprev[s] = hn[s];
            }
            if (lane == 0) {
                pub2(hbuf1 + (size_t)t * 1024, j, hn[0], hn[1]);
                if (t == 256)
#pragma unroll
                    for (int s = 0; s < 2; ++s) e2x[s * 1024 + 512 + j] = hn[s];
            }
            buf ^= 1;
        }
    }
}

// ---------------------------------------------------------------------------
// k_tail: e2-L0 -> e2-L1 -> conv+pool (replicated) -> rnn2 -> head. 32 x 512.
// tb/tr layout: [3 steps][512 rows][2 sentences]
// ---------------------------------------------------------------------------
__global__ __launch_bounds__(512, 1) void k_tail(
    const float* __restrict__ Wih1, const float* __restrict__ bih1,
    const float* __restrict__ Whh1, const float* __restrict__ bhh1,
    const float* __restrict__ convw, const float* __restrict__ convb,
    const float* __restrict__ Whh2, const float* __restrict__ bhh2,
    const float* __restrict__ bih2, const float* __restrict__ Srow,
    const float* __restrict__ e2x,
    const float* __restrict__ WA, const float* __restrict__ WB,
    const float* __restrict__ b_bi, const float* __restrict__ Wlin,
    const float* __restrict__ blin,
    float* __restrict__ tb0, float* __restrict__ tb1, float* __restrict__ tr,
    float* __restrict__ outp)
{
    const int tid = threadIdx.x;
    const int wgi = blockIdx.x;
    const int grp = tid >> 5, lane = tid & 31;
    const int j = wgi * 16 + grp, colbase = lane * 16;
    const size_t WS = (size_t)1536 * 512;

    __shared__ float xlds[1280];
    __shared__ float hlds[1280];
    __shared__ float cwlds[2048];
    __shared__ float part[16];
    __shared__ float red[8];
    __shared__ float smax[4];

    // stage e2x into LDS (plain loads; written by previous dispatch)
    if (tid < 256) {
        const int i = tid * 4, s = i >> 9, k = i & 511;
        float4 v = *(const float4*)(e2x + s * 1024 + k);        // timestep 0
        float* d = xlds + LDSP(i);
        d[0] = v.x; d[1] = v.y; d[2] = v.z; d[3] = v.w;
    } else {
        const int i = (tid - 256) * 4, s = i >> 9, k = i & 511;
        float4 v = *(const float4*)(e2x + s * 1024 + 512 + k);  // timestep 1
        float* d = hlds + LDSP(i);
        d[0] = v.x; d[1] = v.y; d[2] = v.z; d[3] = v.w;
    }
    __syncthreads();

    // ================= stage A: e2-L0 =================
    float gp[2][2][3];
    float bh[3], hp[2];
#pragma unroll
    for (int q = 0; q < 3; ++q) {
        const float* wp = Wih1 + (size_t)(q * 512 + j) * 512 + colbase;
        float w16[16];
#pragma unroll
        for (int c4 = 0; c4 < 4; ++c4) {
            float4 v = *(const float4*)(wp + c4 * 4);
            w16[c4*4+0] = v.x; w16[c4*4+1] = v.y; w16[c4*4+2] = v.z; w16[c4*4+3] = v.w;
        }
        float d00 = 0.f, d01 = 0.f, d10 = 0.f, d11 = 0.f;
#pragma unroll
        for (int c4 = 0; c4 < 4; ++c4) {
            float4 x0 = *(const float4*)&xlds[0 * 640 + 20 * lane + c4 * 4];
            float4 x1 = *(const float4*)&xlds[1 * 640 + 20 * lane + c4 * 4];
            float4 y0 = *(const float4*)&hlds[0 * 640 + 20 * lane + c4 * 4];
            float4 y1 = *(const float4*)&hlds[1 * 640 + 20 * lane + c4 * 4];
            d00 += w16[c4*4+0]*x0.x + w16[c4*4+1]*x0.y + w16[c4*4+2]*x0.z + w16[c4*4+3]*x0.w;
            d01 += w16[c4*4+0]*x1.x + w16[c4*4+1]*x1.y + w16[c4*4+2]*x1.z + w16[c4*4+3]*x1.w;
            d10 += w16[c4*4+0]*y0.x + w16[c4*4+1]*y0.y + w16[c4*4+2]*y0.z + w16[c4*4+3]*y0.w;
            d11 += w16[c4*4+0]*y1.x + w16[c4*4+1]*y1.y + w16[c4*4+2]*y1.z + w16[c4*4+3]*y1.w;
        }
        const float biq = bih1[q * 512 + j];
        gp[0][0][q] = red32(d00) + biq; gp[0][1][q] = red32(d01) + biq;
        gp[1][0][q] = red32(d10) + biq; gp[1][1][q] = red32(d11) + biq;
    }
#pragma unroll
    for (int q = 0; q < 3; ++q) bh[q] = bhh1[q * 512 + j];

#pragma unroll
    for (int s = 0; s < 2; ++s)
        hp[s] = gru1(gp[0][s][0], gp[0][s][1], gp[0][s][2], 0.f, 0.f, 0.f, bh, 0.f);
    if (lane == 0) pub2(tb0 + 1024, j, hp[0], hp[1]);

    __syncthreads();
    if (tid < 256) stage_pollx2(hlds, tb0 + 1024, tid);
    __syncthreads();
    {
        float wh3[3][16];
#pragma unroll
        for (int q = 0; q < 3; ++q) {
            const float* wp = Whh1 + (size_t)(q * 512 + j) * 512 + colbase;
#pragma unroll
            for (int c4 = 0; c4 < 4; ++c4) {
                float4 v = *(const float4*)(wp + c4 * 4);
                wh3[q][c4*4+0] = v.x; wh3[q][c4*4+1] = v.y;
                wh3[q][c4*4+2] = v.z; wh3[q][c4*4+3] = v.w;
            }
        }
        float acc[3][2] = {{0.f,0.f},{0.f,0.f},{0.f,0.f}};
#pragma unroll
        for (int s = 0; s < 2; ++s) {
            const int base = s * 640 + 20 * lane;
#pragma unroll
            for (int c4 = 0; c4 < 4; ++c4) {
                float4 hv = *(const float4*)&hlds[base + c4 * 4];
#pragma unroll
                for (int q = 0; q < 3; ++q)
                    acc[q][s] += wh3[q][c4*4+0]*hv.x + wh3[q][c4*4+1]*hv.y
                               + wh3[q][c4*4+2]*hv.z + wh3[q][c4*4+3]*hv.w;
            }
        }
#pragma unroll
        for (int s = 0; s < 2; ++s) {
            float a0 = red32(acc[0][s]), a1 = red32(acc[1][s]), a2 = red32(acc[2][s]);
            hp[s] = gru1(gp[1][s][0], gp[1][s][1], gp[1][s][2], a0, a1, a2, bh, hp[s]);
        }
        if (lane == 0) pub2(tb0 + 2048, j, hp[0], hp[1]);
    }

    // ================= stage B: e2-L1 =================
    __syncthreads();
    if (tid < 256) stage_pollx2(xlds, tb0 + 1024, tid);
    else           stage_pollx2(hlds, tb0 + 2048, tid - 256);
    __syncthreads();
#pragma unroll
    for (int q = 0; q < 3; ++q) {
        const float* wp = Wih1 + WS + (size_t)(q * 512 + j) * 512 + colbase;
        float w16[16];
#pragma unroll
        for (int c4 = 0; c4 < 4; ++c4) {
            float4 v = *(const float4*)(wp + c4 * 4);
            w16[c4*4+0] = v.x; w16[c4*4+1] = v.y; w16[c4*4+2] = v.z; w16[c4*4+3] = v.w;
        }
        float d00 = 0.f, d01 = 0.f, d10 = 0.f, d11 = 0.f;
#pragma unroll
        for (int c4 = 0; c4 < 4; ++c4) {
            float4 x0 = *(const float4*)&xlds[0 * 640 + 20 * lane + c4 * 4];
            float4 x1 = *(const float4*)&xlds[1 * 640 + 20 * lane + c4 * 4];
            float4 y0 = *(const float4*)&hlds[0 * 640 + 20 * lane + c4 * 4];
            float4 y1 = *(const float4*)&hlds[1 * 640 + 20 * lane + c4 * 4];
            d00 += w16[c4*4+0]*x0.x + w16[c4*4+1]*x0.y + w16[c4*4+2]*x0.z + w16[c4*4+3]*x0.w;
            d01 += w16[c4*4+0]*x1.x + w16[c4*4+1]*x1.y + w16[c4*4+2]*x1.z + w16[c4*4+3]*x1.w;
            d10 += w16[c4*4+0]*y0.x + w16[c4*4+1]*y0.y + w16[c4*4+2]*y0.z + w16[c4*4+3]*y0.w;
            d11 += w16[c4*4+0]*y1.x + w16[c4*4+1]*y1.y + w16[c4*4+2]*y1.z + w16[c4*4+3]*y1.w;
        }
        const float biq = bih1[1536 + q * 512 + j];
        gp[0][0][q] = red32(d00) + biq; gp[0][1][q] = red32(d01) + biq;
        gp[1][0][q] = red32(d10) + biq; gp[1][1][q] = red32(d11) + biq;
    }
#pragma unroll
    for (int q = 0; q < 3; ++q) bh[q] = bhh1[1536 + q * 512 + j];

#pragma unroll
    for (int s = 0; s < 2; ++s)
        hp[s] = gru1(gp[0][s][0], gp[0][s][1], gp[0][s][2], 0.f, 0.f, 0.f, bh, 0.f);
    if (lane == 0) pub2(tb1 + 1024, j, hp[0], hp[1]);

    __syncthreads();
    if (tid < 256) stage_pollx2(hlds, tb1 + 1024, tid);
    __syncthreads();
    {
        float wh3[3][16];
#pragma unroll
        for (int q = 0; q < 3; ++q) {
            const float* wp = Whh1 + WS + (size_t)(q * 512 + j) * 512 + colbase;
#pragma unroll
            for (int c4 = 0; c4 < 4; ++c4) {
                float4 v = *(const float4*)(wp + c4 * 4);
                wh3[q][c4*4+0] = v.x; wh3[q][c4*4+1] = v.y;
                wh3[q][c4*4+2] = v.z; wh3[q][c4*4+3] = v.w;
            }
        }
        float acc[3][2] = {{0.f,0.f},{0.f,0.f},{0.f,0.f}};
#pragma unroll
        for (int s = 0; s < 2; ++s) {
            const int base = s * 640 + 20 * lane;
#pragma unroll
            for (int c4 = 0; c4 < 4; ++c4) {
                float4 hv = *(const float4*)&hlds[base + c4 * 4];
#pragma unroll
                for (int q = 0; q < 3; ++q)
                    acc[q][s] += wh3[q][c4*4+0]*hv.x + wh3[q][c4*4+1]*hv.y
                               + wh3[q][c4*4+2]*hv.z + wh3[q][c4*4+3]*hv.w;
            }
        }
#pragma unroll
        for (int s = 0; s < 2; ++s) {
            float a0 = red32(acc[0][s]), a1 = red32(acc[1][s]), a2 = red32(acc[2][s]);
            hp[s] = gru1(gp[1][s][0], gp[1][s][1], gp[1][s][2], a0, a1, a2, bh, hp[s]);
        }
        if (lane == 0) pub2(tb1 + 2048, j, hp[0], hp[1]);
    }

    // ======== stage C: conv + global max pool (replicated in every WG) ========
    __syncthreads();
    if (tid < 256) {
        stage_pollx2(xlds, tb0 + 2048, tid);        // finals L0 [s][512]
        const int b8 = tid * 8;
#pragma unroll
        for (int u = 0; u < 8; ++u) cwlds[b8 + u] = convw[b8 + u];
    } else {
        stage_pollx2(hlds, tb1 + 2048, tid - 256);  // finals L1 [s][512]
    }
    __syncthreads();
#pragma unroll
    for (int oo = 0; oo < 2; ++oo) {
        const int w = tid + oo * 512;
        const int so = w >> 8, pos = w & 255;
        const int s = so >> 1, o = so & 1;
        float acc = convb[o];
        const int base = 2 * pos - 255;
        for (int k = 0; k < 512; ++k) {
            const int p2 = base + k;
            if ((unsigned)p2 < 512u) {
                const int gi0i = s * 512 + p2;
                acc += xlds[LDSP(gi0i)] * cwlds[(o * 2 + 0) * 512 + k]
                     + hlds[LDSP(gi0i)] * cwlds[(o * 2 + 1) * 512 + k];
            }
        }
        float m = acc;
        m = fmaxf(m, __shfl_xor(m, 32, 64));
        m = fmaxf(m, __shfl_xor(m, 16, 64));
        m = fmaxf(m, __shfl_xor(m, 8, 64));
        m = fmaxf(m, __shfl_xor(m, 4, 64));
        m = fmaxf(m, __shfl_xor(m, 2, 64));
        m = fmaxf(m, __shfl_xor(m, 1, 64));
        if ((tid & 63) == 0) part[oo * 8 + (tid >> 6)] = m;   // so uniform per wave
    }
    __syncthreads();
    if (tid < 4) {
        float mm = -3.4e38f;
        for (int p = 0; p < 16; ++p) {
            const int so_p = ((p & 7) >> 2) + 2 * (p >> 3);
            if (so_p == tid) mm = fmaxf(mm, part[p]);
        }
        smax[tid] = mm;
    }
    __syncthreads();
    float m4[4];
#pragma unroll
    for (int i = 0; i < 4; ++i) m4[i] = smax[i];

    // ================= stage D: rnn2 (T=2, gi = Mmax*Srow + bih2) =================
    {
        float wh3[3][16];
#pragma unroll
        for (int q = 0; q < 3; ++q) {
            const float* wp = Whh2 + (size_t)(q * 512 + j) * 512 + colbase;
#pragma unroll
            for (int c4 = 0; c4 < 4; ++c4) {
                float4 v = *(const float4*)(wp + c4 * 4);
                wh3[q][c4*4+0] = v.x; wh3[q][c4*4+1] = v.y;
                wh3[q][c4*4+2] = v.z; wh3[q][c4*4+3] = v.w;
            }
        }
#pragma unroll
        for (int q = 0; q < 3; ++q) {
            const float sq = Srow[q * 512 + j];
            const float biq = bih2[q * 512 + j];
#pragma unroll
            for (int s = 0; s < 2; ++s) {
                gp[0][s][q] = m4[s * 2 + 0] * sq + biq;
                gp[1][s][q] = m4[s * 2 + 1] * sq + biq;
            }
            bh[q] = bhh2[q * 512 + j];
        }
#pragma unroll
        for (int s = 0; s < 2; ++s)
            hp[s] = gru1(gp[0][s][0], gp[0][s][1], gp[0][s][2], 0.f, 0.f, 0.f, bh, 0.f);
        if (lane == 0) pub2(tr + 1024, j, hp[0], hp[1]);

        __syncthreads();                   // conv reads of hlds done
        if (tid < 256) stage_pollx2(hlds, tr + 1024, tid);
        __syncthreads();
        float acc[3][2] = {{0.f,0.f},{0.f,0.f},{0.f,0.f}};
#pragma unroll
        for (int s = 0; s < 2; ++s) {
            const int base = s * 640 + 20 * lane;
#pragma unroll
            for (int c4 = 0; c4 < 4; ++c4) {
                float4 hv = *(const float4*)&hlds[base + c4 * 4];
#pragma unroll
                for (int q = 0; q < 3; ++q)
                    acc[q][s] += wh3[q][c4*4+0]*hv.x + wh3[q][c4*4+1]*hv.y
                               + wh3[q][c4*4+2]*hv.z + wh3[q][c4*4+3]*hv.w;
            }
        }
#pragma unroll
        for (int s = 0; s < 2; ++s) {
            float a0 = red32(acc[0][s]), a1 = red32(acc[1][s]), a2 = red32(acc[2][s]);
            hp[s] = gru1(gp[1][s][0], gp[1][s][1], gp[1][s][2], a0, a1, a2, bh, hp[s]);
        }
        if (lane == 0) pub2(tr + 2048, j, hp[0], hp[1]);
    }

    // ================= stage E: similarity head (WG0 only) =================
    if (wgi != 0) return;
    __syncthreads();
    if (tid < 256) stage_pollx2(xlds, tr + 2048, tid);  // [s][512]: hA, hB
    __syncthreads();
    float v = 0.f;
    if (tid < 256) {
        float acc = b_bi[tid];
        for (int jj = 0; jj < 512; ++jj) {
            const float a = xlds[LDSP(jj)];
            const float b = xlds[LDSP(512 + jj)];
            acc += (a * b) * WA[(size_t)jj * 256 + tid]
                 + fabsf(a - b) * WB[(size_t)jj * 256 + tid];
        }
        v = tanhf(acc) * Wlin[tid];
    }
    v += __shfl_xor(v, 32, 64);
    v += __shfl_xor(v, 16, 64);
    v += __shfl_xor(v, 8, 64);
    v += __shfl_xor(v, 4, 64);
    v += __shfl_xor(v, 2, 64);
    v += __shfl_xor(v, 1, 64);
    if ((tid & 63) == 0) red[tid >> 6] = v;
    __syncthreads();
    if (tid == 0) {
        float ssum = blin[0];
        for (int i = 0; i < 8; ++i) ssum += red[i];
        outp[0] = 1.f / (1.f + expf(-ssum));
    }
}

// ---------------------------------------------------------------------------
// init: poison hbuf0/hbuf1 (t=1..256) + tb0/tb1/tr (steps 1..2);
// Srow[r] = sum_k Wih2[r][k] (k<128). Re-poison runs every launch (graph-safe).
// ---------------------------------------------------------------------------
__global__ __launch_bounds__(256) void k_init(
    const float* __restrict__ Wih2, float* __restrict__ Srow,
    unsigned int* __restrict__ hb0, unsigned int* __restrict__ hb1,
    unsigned int* __restrict__ tb0u, unsigned int* __restrict__ tb1u,
    unsigned int* __restrict__ tru)
{
    const int g = blockIdx.x * 256 + threadIdx.x;
    if (g < 1536) {
        float s = 0.f;
        for (int k = 0; k < 128; ++k) s += Wih2[(size_t)g * 128 + k];
        Srow[g] = s;
    }
    if (g < 2048) {
        tb0u[1024 + g] = CANARY_U;
        tb1u[1024 + g] = CANARY_U;
        tru[1024 + g]  = CANARY_U;
    }
    const int N = 256 * 1024;                 // words per hbuf, t=1..256
    const int stride = gridDim.x * 256;
    for (int i = g; i < N; i += stride) {
        hb0[1024 + i] = CANARY_U;
        hb1[1024 + i] = CANARY_U;
    }
}

// ---------------------------------------------------------------------------
extern "C" void kernel_launch(void* const* d_in, const int* in_sizes, int n_in,
                              void* d_out, int out_size, void* d_ws, size_t ws_size,
                              hipStream_t stream)
{
    const int*   sentA = (const int*)d_in[0];
    const int*   sentB = (const int*)d_in[1];
    const float* emb   = (const float*)d_in[2];
    const float* Wih1  = (const float*)d_in[3];   // [2][1536][512]
    const float* Whh1  = (const float*)d_in[4];   // [2][1536][512]
    const float* bih1  = (const float*)d_in[5];   // [2][1536]
    const float* bhh1  = (const float*)d_in[6];   // [2][1536]
    const float* convw = (const float*)d_in[7];   // [2][2][512]
    const float* convb = (const float*)d_in[8];   // [2]
    const float* Wih2  = (const float*)d_in[9];   // [1536][128]
    const float* Whh2  = (const float*)d_in[10];  // [1536][512]
    const float* bih2  = (const float*)d_in[11];  // [1536]
    const float* bhh2  = (const float*)d_in[12];  // [1536]
    const float* WA    = (const float*)d_in[13];  // [512][256]
    const float* WB    = (const float*)d_in[14];  // [512][256]
    const float* b_bi  = (const float*)d_in[15];  // [256]
    const float* Wlin  = (const float*)d_in[16];  // [1][256]
    const float* blin  = (const float*)d_in[17];  // [1]

    float* ws = (float*)d_ws;
    size_t off = 0;
    float* e2x    = ws + off; off += 2048;        // [2 sent][2 layer][512]
    float* hbuf0  = ws + off; off += 257 * 1024;  // [257][512][2]
    float* hbuf1  = ws + off; off += 257 * 1024;  // [257][512][2]
    float* tb0    = ws + off; off += 3 * 1024;    // [3][512][2]
    float* tb1    = ws + off; off += 3 * 1024;
    float* tr     = ws + off; off += 3 * 1024;
    float* Srow   = ws + off; off += 1536;

    k_init<<<256, 256, 0, stream>>>(Wih2, Srow,
                                    (unsigned int*)hbuf0, (unsigned int*)hbuf1,
                                    (unsigned int*)tb0, (unsigned int*)tb1,
                                    (unsigned int*)tr);

    k_pipe<<<64, 512, 0, stream>>>(Whh1, bhh1, Wih1, bih1, emb, sentA, sentB,
                                   e2x, hbuf0, hbuf1);

    k_tail<<<32, 512, 0, stream>>>(Wih1, bih1, Whh1, bhh1, convw, convb,
                                   Whh2, bhh2, bih2, Srow, e2x,
                                   WA, WB, b_bi, Wlin, blin,
                                   tb0, tb1, tr, (float*)d_out);
}

// Round 10
// 1261.015 us; speedup vs baseline: 1.0303x; 1.0303x over previous
//
#include <hip/hip_runtime.h>
#include <math.h>

// ---------------------------------------------------------------------------
// Com_CNN_RNN R15 (base = R13, best total 1271.9us):
//  k_tail MERGED into k_pipe. Sync floor (~3.6us/hop, protocol-invariant
//  across 6 families R5-R14) is structural: weights must stay distributed
//  across 32 CUs (3MB/layer >> 512KB/CU regfile) -> per-step all-gather is
//  unavoidable. So attack the non-pipe residue instead:
//   - e2-L0 runs on L0 WGs with ALREADY-RESIDENT wi/wh (no weight reload),
//     e2-L1 on L1 WGs likewise; conv/rnn2/head on L0 WGs; head on WG0.
//   - deletes the k_tail launch boundary, e2x handoff, tail weight reloads.
//   - Srow folded into phase D (12 loads/thread + red32).
//  Poll/pub identical to R13 (plain relaxed agent loads/stores + VALU heater,
//  SPIN_HOT 65536). Canary = FLT_MAX bits (|GRU h| < 1 strictly).
//  k_init re-poisons hbuf0/hbuf1/tb0/tb1/tr every launch (graph-replay safe).
// ---------------------------------------------------------------------------

#define CANARY_U 0x7F7FFFFFu
#define SPIN_HOT 65536

__device__ __forceinline__ float sigm(float x) { return 1.f / (1.f + expf(-x)); }

// LDS index map: p(k) = k + (k>>4)*4 (pad 4 words per 16; keeps float4 align)
#define LDSP(k) ((k) + (((k) >> 4) << 2))

__device__ __forceinline__ float red32(float v) {
    v += __shfl_xor(v, 16, 64);
    v += __shfl_xor(v, 8, 64);
    v += __shfl_xor(v, 4, 64);
    v += __shfl_xor(v, 2, 64);
    v += __shfl_xor(v, 1, 64);
    return v;
}

// VALU heater (R13 config; kept for identical poll behavior)
#define HEAT_DECL  float hh0=1.f,hh1=1.01f,hh2=1.02f,hh3=1.03f, \
                         hh4=1.04f,hh5=1.05f,hh6=1.06f,hh7=1.07f
#define HEAT_STEP  do { _Pragma("unroll") \
    for (int _d = 0; _d < 8; ++_d) { \
        hh0=__builtin_fmaf(hh0,1.0000001f,1e-7f); hh1=__builtin_fmaf(hh1,1.0000001f,1e-7f); \
        hh2=__builtin_fmaf(hh2,1.0000001f,1e-7f); hh3=__builtin_fmaf(hh3,1.0000001f,1e-7f); \
        hh4=__builtin_fmaf(hh4,1.0000001f,1e-7f); hh5=__builtin_fmaf(hh5,1.0000001f,1e-7f); \
        hh6=__builtin_fmaf(hh6,1.0000001f,1e-7f); hh7=__builtin_fmaf(hh7,1.0000001f,1e-7f); \
    } } while (0)
#define HEAT_SINK  asm volatile("" :: "v"(hh0),"v"(hh1),"v"(hh2),"v"(hh3), \
                                      "v"(hh4),"v"(hh5),"v"(hh6),"v"(hh7))

// Publisher: half-wave lane0 packs h for both sentences of row j into 8B.
__device__ __forceinline__ void pub2(float* base, int j, float h0, float h1) {
    union { float2 f; unsigned long long u; } p;
    p.f = make_float2(h0, h1);
    __hip_atomic_store((unsigned long long*)base + j, p.u,
                       __ATOMIC_RELAXED, __HIP_MEMORY_SCOPE_AGENT);
}

// Poll ONE row (8B: both sentences) of src [512][2]; thread i covers row i.
__device__ __forceinline__ void stage_poll8(float* dst, const float* src, int i) {
    const unsigned long long* s = (const unsigned long long*)src + i;
    unsigned long long a;
    int it = 0;
    HEAT_DECL;
    for (;;) {
        a = __hip_atomic_load(s, __ATOMIC_RELAXED, __HIP_MEMORY_SCOPE_AGENT);
        if ((unsigned int)a != CANARY_U && (unsigned int)(a >> 32) != CANARY_U)
            break;
        HEAT_STEP;
        if (++it > SPIN_HOT) __builtin_amdgcn_s_sleep(1);
    }
    HEAT_SINK;
    union { unsigned long long u; float2 f; } c; c.u = a;
    dst[LDSP(i)]       = c.f.x;      // sent0 row i
    dst[LDSP(512 + i)] = c.f.y;      // sent1 row i
}

// Poll TWO rows (16B) of src [512][2]; thread i covers rows 2i, 2i+1.
__device__ __forceinline__ void stage_pollx2(float* dst, const float* src, int i) {
    const unsigned long long* s = (const unsigned long long*)src + (size_t)i * 2;
    unsigned long long a, b;
    int it = 0;
    HEAT_DECL;
    for (;;) {
        a = __hip_atomic_load(s + 0, __ATOMIC_RELAXED, __HIP_MEMORY_SCOPE_AGENT);
        b = __hip_atomic_load(s + 1, __ATOMIC_RELAXED, __HIP_MEMORY_SCOPE_AGENT);
        if ((unsigned int)a != CANARY_U && (unsigned int)(a >> 32) != CANARY_U &&
            (unsigned int)b != CANARY_U && (unsigned int)(b >> 32) != CANARY_U)
            break;
        HEAT_STEP;
        if (++it > SPIN_HOT) __builtin_amdgcn_s_sleep(1);
    }
    HEAT_SINK;
    union { unsigned long long u; float2 f; } c0, c1;
    c0.u = a; c1.u = b;
    const int r0 = 2 * i, r1 = 2 * i + 1;
    dst[LDSP(r0)]       = c0.f.x;
    dst[LDSP(512 + r0)] = c0.f.y;
    dst[LDSP(r1)]       = c1.f.x;
    dst[LDSP(512 + r1)] = c1.f.y;
}

__device__ __forceinline__ float gru1(float gr, float gz, float gn,
                                      float ar, float az, float an,
                                      const float bh[3], float hp) {
    float r = sigm(gr + ar + bh[0]);
    float z = sigm(gz + az + bh[1]);
    float n = tanhf(gn + r * (an + bh[2]));
    return (1.f - z) * n + z * hp;
}

// ---------------------------------------------------------------------------
// k_pipe: epoch-1 L0+L1 pipelined + FUSED TAIL. grid 64 x 512.
// hbuf layout: [257 steps][512 rows][2 sent]; tb/tr: [3 steps][512 rows][2]
// ---------------------------------------------------------------------------
__global__ __launch_bounds__(512, 1) void k_pipe(
    const float* __restrict__ Whh1, const float* __restrict__ bhh1,
    const float* __restrict__ Wih1, const float* __restrict__ bih1,
    const float* __restrict__ emb,
    const int* __restrict__ sentA, const int* __restrict__ sentB,
    const float* __restrict__ convw, const float* __restrict__ convb,
    const float* __restrict__ Whh2, const float* __restrict__ bhh2,
    const float* __restrict__ bih2, const float* __restrict__ Wih2,
    const float* __restrict__ WA, const float* __restrict__ WB,
    const float* __restrict__ b_bi, const float* __restrict__ Wlin,
    const float* __restrict__ blin,
    float* __restrict__ hbuf0, float* __restrict__ hbuf1,
    float* __restrict__ tb0, float* __restrict__ tb1, float* __restrict__ tr,
    float* __restrict__ outp)
{
    const int tid   = threadIdx.x;
    const int layer = blockIdx.x >> 5;    // 0 or 1
    const int wgi   = blockIdx.x & 31;
    const int grp   = tid >> 5;           // 0..15 (32-lane half-wave groups)
    const int lane  = tid & 31;
    const int j     = wgi * 16 + grp;     // h row 0..511
    const int colbase = lane * 16;

    __shared__ float xlds[2][1280];
    __shared__ float hlds[2][1280];
    __shared__ float cwlds[2048];
    __shared__ float part[16];
    __shared__ float redl[8];
    __shared__ float smax[4];

    const size_t WS = (size_t)1536 * 512;
    const float* WH = Whh1 + (size_t)layer * WS;
    const float* WI = Wih1 + (size_t)layer * WS;

    // recurrent + input weights register-resident (48 + 48 floats)
    float wh[3][16], wi[3][16];
#pragma unroll
    for (int q = 0; q < 3; ++q) {
        const float* srch = WH + (size_t)(q * 512 + j) * 512 + colbase;
        const float* srci = WI + (size_t)(q * 512 + j) * 512 + colbase;
#pragma unroll
        for (int c4 = 0; c4 < 4; ++c4) {
            float4 v = *(const float4*)(srch + c4 * 4);
            wh[q][c4*4+0] = v.x; wh[q][c4*4+1] = v.y;
            wh[q][c4*4+2] = v.z; wh[q][c4*4+3] = v.w;
            float4 w = *(const float4*)(srci + c4 * 4);
            wi[q][c4*4+0] = w.x; wi[q][c4*4+1] = w.y;
            wi[q][c4*4+2] = w.z; wi[q][c4*4+3] = w.w;
        }
    }
#pragma unroll
    for (int q = 0; q < 3; ++q)
#pragma unroll
        for (int c = 0; c < 16; ++c) {
            asm volatile("" : "+v"(wh[q][c]));
            asm volatile("" : "+v"(wi[q][c]));
        }

    float bh[3], bi[3];
#pragma unroll
    for (int q = 0; q < 3; ++q) {
        bh[q] = bhh1[layer * 1536 + q * 512 + j];
        bi[q] = bih1[layer * 1536 + q * 512 + j];
    }

    float hprev[2] = {0.f, 0.f};
    int buf = 0;

    // ========================= epoch-1 main loop =========================
    if (layer == 0) {
        for (int t = 1; t <= 256; ++t) {
            const int ta = sentA[t - 1], tb = sentB[t - 1];
            const float* xa = emb + (size_t)ta * 512 + colbase;
            const float* xb = emb + (size_t)tb * 512 + colbase;
            float4 xav[4], xbv[4];
#pragma unroll
            for (int c4 = 0; c4 < 4; ++c4) {
                xav[c4] = *(const float4*)(xa + c4 * 4);
                xbv[c4] = *(const float4*)(xb + c4 * 4);
            }

            if (t > 1) {
                stage_poll8(xlds[buf], hbuf0 + (size_t)(t - 1) * 1024, tid);
                __syncthreads();
            }

            float aR[2] = {0.f,0.f}, aZ[2] = {0.f,0.f};
            float aGN[2] = {0.f,0.f}, aHN[2] = {0.f,0.f};
#pragma unroll
            for (int s = 0; s < 2; ++s) {
                const float4* xv = s ? xbv : xav;
#pragma unroll
                for (int c4 = 0; c4 < 4; ++c4) {
                    const float4 v = xv[c4];
                    aR[s]  += wi[0][c4*4+0]*v.x + wi[0][c4*4+1]*v.y
                            + wi[0][c4*4+2]*v.z + wi[0][c4*4+3]*v.w;
                    aZ[s]  += wi[1][c4*4+0]*v.x + wi[1][c4*4+1]*v.y
                            + wi[1][c4*4+2]*v.z + wi[1][c4*4+3]*v.w;
                    aGN[s] += wi[2][c4*4+0]*v.x + wi[2][c4*4+1]*v.y
                            + wi[2][c4*4+2]*v.z + wi[2][c4*4+3]*v.w;
                }
                if (t > 1) {
                    const int base = s * 640 + 20 * lane;
#pragma unroll
                    for (int c4 = 0; c4 < 4; ++c4) {
                        float4 hv = *(const float4*)&xlds[buf][base + c4 * 4];
                        aR[s]  += wh[0][c4*4+0]*hv.x + wh[0][c4*4+1]*hv.y
                                + wh[0][c4*4+2]*hv.z + wh[0][c4*4+3]*hv.w;
                        aZ[s]  += wh[1][c4*4+0]*hv.x + wh[1][c4*4+1]*hv.y
                                + wh[1][c4*4+2]*hv.z + wh[1][c4*4+3]*hv.w;
                        aHN[s] += wh[2][c4*4+0]*hv.x + wh[2][c4*4+1]*hv.y
                                + wh[2][c4*4+2]*hv.z + wh[2][c4*4+3]*hv.w;
                    }
                }
            }
#pragma unroll
            for (int s = 0; s < 2; ++s) {
                aR[s] = red32(aR[s]); aZ[s] = red32(aZ[s]);
                aGN[s] = red32(aGN[s]); aHN[s] = red32(aHN[s]);
            }
            float hn[2];
#pragma unroll
            for (int s = 0; s < 2; ++s) {
                float r = sigm(aR[s] + bi[0] + bh[0]);
                float z = sigm(aZ[s] + bi[1] + bh[1]);
                float n = tanhf(aGN[s] + bi[2] + r * (aHN[s] + bh[2]));
                hn[s] = (1.f - z) * n + z * hprev[s];
                hprev[s] = hn[s];
            }
            if (lane == 0) pub2(hbuf0 + (size_t)t * 1024, j, hn[0], hn[1]);
            buf ^= 1;
        }
    } else {
        for (int t = 1; t <= 256; ++t) {
            if (tid < 256)
                stage_pollx2(xlds[buf], hbuf0 + (size_t)t * 1024, tid);
            else if (t > 1)
                stage_pollx2(hlds[buf], hbuf1 + (size_t)(t - 1) * 1024, tid - 256);
            __syncthreads();

            float aR[2] = {0.f,0.f}, aZ[2] = {0.f,0.f};
            float aGN[2] = {0.f,0.f}, aHN[2] = {0.f,0.f};
#pragma unroll
            for (int s = 0; s < 2; ++s) {
                const int base = s * 640 + 20 * lane;
#pragma unroll
                for (int c4 = 0; c4 < 4; ++c4) {
                    float4 xv = *(const float4*)&xlds[buf][base + c4 * 4];
                    aR[s]  += wi[0][c4*4+0]*xv.x + wi[0][c4*4+1]*xv.y
                            + wi[0][c4*4+2]*xv.z + wi[0][c4*4+3]*xv.w;
                    aZ[s]  += wi[1][c4*4+0]*xv.x + wi[1][c4*4+1]*xv.y
                            + wi[1][c4*4+2]*xv.z + wi[1][c4*4+3]*xv.w;
                    aGN[s] += wi[2][c4*4+0]*xv.x + wi[2][c4*4+1]*xv.y
                            + wi[2][c4*4+2]*xv.z + wi[2][c4*4+3]*xv.w;
                }
                if (t > 1) {
#pragma unroll
                    for (int c4 = 0; c4 < 4; ++c4) {
                        float4 hv = *(const float4*)&hlds[buf][base + c4 * 4];
                        aR[s]  += wh[0][c4*4+0]*hv.x + wh[0][c4*4+1]*hv.y
                                + wh[0][c4*4+2]*hv.z + wh[0][c4*4+3]*hv.w;
                        aZ[s]  += wh[1][c4*4+0]*hv.x + wh[1][c4*4+1]*hv.y
                                + wh[1][c4*4+2]*hv.z + wh[1][c4*4+3]*hv.w;
                        aHN[s] += wh[2][c4*4+0]*hv.x + wh[2][c4*4+1]*hv.y
                                + wh[2][c4*4+2]*hv.z + wh[2][c4*4+3]*hv.w;
                    }
                }
            }
#pragma unroll
            for (int s = 0; s < 2; ++s) {
                aR[s] = red32(aR[s]); aZ[s] = red32(aZ[s]);
                aGN[s] = red32(aGN[s]); aHN[s] = red32(aHN[s]);
            }
            float hn[2];
#pragma unroll
            for (int s = 0; s < 2; ++s) {
                float r = sigm(aR[s] + bi[0] + bh[0]);
                float z = sigm(aZ[s] + bi[1] + bh[1]);
                float n = tanhf(aGN[s] + bi[2] + r * (aHN[s] + bh[2]));
                hn[s] = (1.f - z) * n + z * hprev[s];
                hprev[s] = hn[s];
            }
            if (lane == 0) pub2(hbuf1 + (size_t)t * 1024, j, hn[0], hn[1]);
            buf ^= 1;
        }
    }

    // ========================= fused tail =========================
    float gp[2][2][3], hp[2];

    if (layer == 1) {
        // ---------- phase B: e2-L1 on L1 WGs (wi/wh/bi/bh resident) ----------
        __syncthreads();
        if (tid < 256) stage_pollx2(xlds[0], tb0 + 1024, tid);        // x step0
        else           stage_pollx2(hlds[0], tb0 + 2048, tid - 256);  // x step1
        __syncthreads();
#pragma unroll
        for (int q = 0; q < 3; ++q) {
            float d00 = 0.f, d01 = 0.f, d10 = 0.f, d11 = 0.f;
#pragma unroll
            for (int c4 = 0; c4 < 4; ++c4) {
                float4 x0 = *(const float4*)&xlds[0][0 * 640 + 20 * lane + c4 * 4];
                float4 x1 = *(const float4*)&xlds[0][1 * 640 + 20 * lane + c4 * 4];
                float4 y0 = *(const float4*)&hlds[0][0 * 640 + 20 * lane + c4 * 4];
                float4 y1 = *(const float4*)&hlds[0][1 * 640 + 20 * lane + c4 * 4];
                d00 += wi[q][c4*4+0]*x0.x + wi[q][c4*4+1]*x0.y + wi[q][c4*4+2]*x0.z + wi[q][c4*4+3]*x0.w;
                d01 += wi[q][c4*4+0]*x1.x + wi[q][c4*4+1]*x1.y + wi[q][c4*4+2]*x1.z + wi[q][c4*4+3]*x1.w;
                d10 += wi[q][c4*4+0]*y0.x + wi[q][c4*4+1]*y0.y + wi[q][c4*4+2]*y0.z + wi[q][c4*4+3]*y0.w;
                d11 += wi[q][c4*4+0]*y1.x + wi[q][c4*4+1]*y1.y + wi[q][c4*4+2]*y1.z + wi[q][c4*4+3]*y1.w;
            }
            gp[0][0][q] = red32(d00) + bi[q]; gp[0][1][q] = red32(d01) + bi[q];
            gp[1][0][q] = red32(d10) + bi[q]; gp[1][1][q] = red32(d11) + bi[q];
        }
#pragma unroll
        for (int s = 0; s < 2; ++s)
            hp[s] = gru1(gp[0][s][0], gp[0][s][1], gp[0][s][2], 0.f, 0.f, 0.f, bh, 0.f);
        if (lane == 0) pub2(tb1 + 1024, j, hp[0], hp[1]);

        __syncthreads();
        if (tid < 256) stage_pollx2(hlds[0], tb1 + 1024, tid);
        __syncthreads();
        {
            float acc[3][2] = {{0.f,0.f},{0.f,0.f},{0.f,0.f}};
#pragma unroll
            for (int s = 0; s < 2; ++s) {
                const int base = s * 640 + 20 * lane;
#pragma unroll
                for (int c4 = 0; c4 < 4; ++c4) {
                    float4 hv = *(const float4*)&hlds[0][base + c4 * 4];
#pragma unroll
                    for (int q = 0; q < 3; ++q)
                        acc[q][s] += wh[q][c4*4+0]*hv.x + wh[q][c4*4+1]*hv.y
                                   + wh[q][c4*4+2]*hv.z + wh[q][c4*4+3]*hv.w;
                }
            }
#pragma unroll
            for (int s = 0; s < 2; ++s) {
                float a0 = red32(acc[0][s]), a1 = red32(acc[1][s]), a2 = red32(acc[2][s]);
                hp[s] = gru1(gp[1][s][0], gp[1][s][1], gp[1][s][2], a0, a1, a2, bh, hp[s]);
            }
            if (lane == 0) pub2(tb1 + 2048, j, hp[0], hp[1]);
        }
        return;   // L1 WGs done
    }

    // ---------- phase A: e2-L0 on L0 WGs (wi/wh/bi/bh resident) ----------
    __syncthreads();
    if (tid < 256) stage_pollx2(xlds[0], hbuf0 + (size_t)256 * 1024, tid);       // x step0
    else           stage_pollx2(hlds[0], hbuf1 + (size_t)256 * 1024, tid - 256); // x step1
    __syncthreads();
#pragma unroll
    for (int q = 0; q < 3; ++q) {
        float d00 = 0.f, d01 = 0.f, d10 = 0.f, d11 = 0.f;
#pragma unroll
        for (int c4 = 0; c4 < 4; ++c4) {
            float4 x0 = *(const float4*)&xlds[0][0 * 640 + 20 * lane + c4 * 4];
            float4 x1 = *(const float4*)&xlds[0][1 * 640 + 20 * lane + c4 * 4];
            float4 y0 = *(const float4*)&hlds[0][0 * 640 + 20 * lane + c4 * 4];
            float4 y1 = *(const float4*)&hlds[0][1 * 640 + 20 * lane + c4 * 4];
            d00 += wi[q][c4*4+0]*x0.x + wi[q][c4*4+1]*x0.y + wi[q][c4*4+2]*x0.z + wi[q][c4*4+3]*x0.w;
            d01 += wi[q][c4*4+0]*x1.x + wi[q][c4*4+1]*x1.y + wi[q][c4*4+2]*x1.z + wi[q][c4*4+3]*x1.w;
            d10 += wi[q][c4*4+0]*y0.x + wi[q][c4*4+1]*y0.y + wi[q][c4*4+2]*y0.z + wi[q][c4*4+3]*y0.w;
            d11 += wi[q][c4*4+0]*y1.x + wi[q][c4*4+1]*y1.y + wi[q][c4*4+2]*y1.z + wi[q][c4*4+3]*y1.w;
        }
        gp[0][0][q] = red32(d00) + bi[q]; gp[0][1][q] = red32(d01) + bi[q];
        gp[1][0][q] = red32(d10) + bi[q]; gp[1][1][q] = red32(d11) + bi[q];
    }
#pragma unroll
    for (int s = 0; s < 2; ++s)
        hp[s] = gru1(gp[0][s][0], gp[0][s][1], gp[0][s][2], 0.f, 0.f, 0.f, bh, 0.f);
    if (lane == 0) pub2(tb0 + 1024, j, hp[0], hp[1]);

    __syncthreads();
    if (tid < 256) stage_pollx2(hlds[0], tb0 + 1024, tid);
    __syncthreads();
    {
        float acc[3][2] = {{0.f,0.f},{0.f,0.f},{0.f,0.f}};
#pragma unroll
        for (int s = 0; s < 2; ++s) {
            const int base = s * 640 + 20 * lane;
#pragma unroll
            for (int c4 = 0; c4 < 4; ++c4) {
                float4 hv = *(const float4*)&hlds[0][base + c4 * 4];
#pragma unroll
                for (int q = 0; q < 3; ++q)
                    acc[q][s] += wh[q][c4*4+0]*hv.x + wh[q][c4*4+1]*hv.y
                               + wh[q][c4*4+2]*hv.z + wh[q][c4*4+3]*hv.w;
            }
        }
#pragma unroll
        for (int s = 0; s < 2; ++s) {
            float a0 = red32(acc[0][s]), a1 = red32(acc[1][s]), a2 = red32(acc[2][s]);
            hp[s] = gru1(gp[1][s][0], gp[1][s][1], gp[1][s][2], a0, a1, a2, bh, hp[s]);
        }
        if (lane == 0) pub2(tb0 + 2048, j, hp[0], hp[1]);
    }

    // ---------- phase C: conv + global maxpool (replicated on L0 WGs) ----------
    __syncthreads();
    if (tid < 256) {
        stage_pollx2(xlds[0], tb0 + 2048, tid);          // finals L0 [s][512]
        const int b8 = tid * 8;
#pragma unroll
        for (int u = 0; u < 8; ++u) cwlds[b8 + u] = convw[b8 + u];
    } else {
        stage_pollx2(hlds[0], tb1 + 2048, tid - 256);    // finals L1 [s][512]
    }
    __syncthreads();
#pragma unroll
    for (int oo = 0; oo < 2; ++oo) {
        const int w = tid + oo * 512;
        const int so = w >> 8, pos = w & 255;
        const int s = so >> 1, o = so & 1;
        float acc = convb[o];
        const int base = 2 * pos - 255;
        for (int k = 0; k < 512; ++k) {
            const int p2 = base + k;
            if ((unsigned)p2 < 512u) {
                const int gi0i = s * 512 + p2;
                acc += xlds[0][LDSP(gi0i)] * cwlds[(o * 2 + 0) * 512 + k]
                     + hlds[0][LDSP(gi0i)] * cwlds[(o * 2 + 1) * 512 + k];
            }
        }
        float m = acc;
        m = fmaxf(m, __shfl_xor(m, 32, 64));
        m = fmaxf(m, __shfl_xor(m, 16, 64));
        m = fmaxf(m, __shfl_xor(m, 8, 64));
        m = fmaxf(m, __shfl_xor(m, 4, 64));
        m = fmaxf(m, __shfl_xor(m, 2, 64));
        m = fmaxf(m, __shfl_xor(m, 1, 64));
        if ((tid & 63) == 0) part[oo * 8 + (tid >> 6)] = m;   // so uniform per wave
    }
    __syncthreads();
    if (tid < 4) {
        float mm = -3.4e38f;
        for (int p = 0; p < 16; ++p) {
            const int so_p = ((p & 7) >> 2) + 2 * (p >> 3);
            if (so_p == tid) mm = fmaxf(mm, part[p]);
        }
        smax[tid] = mm;
    }
    __syncthreads();
    float m4[4];
#pragma unroll
    for (int i = 0; i < 4; ++i) m4[i] = smax[i];

    // ---------- phase D: rnn2 (T=2); Srow computed inline ----------
    {
        float wh3[3][16], bh2[3];
#pragma unroll
        for (int q = 0; q < 3; ++q) {
            const float* wp = Whh2 + (size_t)(q * 512 + j) * 512 + colbase;
#pragma unroll
            for (int c4 = 0; c4 < 4; ++c4) {
                float4 v = *(const float4*)(wp + c4 * 4);
                wh3[q][c4*4+0] = v.x; wh3[q][c4*4+1] = v.y;
                wh3[q][c4*4+2] = v.z; wh3[q][c4*4+3] = v.w;
            }
        }
#pragma unroll
        for (int q = 0; q < 3; ++q) {
            // Srow[q*512+j] = sum_{k<128} Wih2[(q*512+j)*128 + k], lane-split
            const float* wr = Wih2 + (size_t)(q * 512 + j) * 128 + lane * 4;
            float s4 = wr[0] + wr[1] + wr[2] + wr[3];
            const float sq = red32(s4);
            const float biq = bih2[q * 512 + j];
#pragma unroll
            for (int s = 0; s < 2; ++s) {
                gp[0][s][q] = m4[s * 2 + 0] * sq + biq;
                gp[1][s][q] = m4[s * 2 + 1] * sq + biq;
            }
            bh2[q] = bhh2[q * 512 + j];
        }
#pragma unroll
        for (int s = 0; s < 2; ++s)
            hp[s] = gru1(gp[0][s][0], gp[0][s][1], gp[0][s][2], 0.f, 0.f, 0.f, bh2, 0.f);
        if (lane == 0) pub2(tr + 1024, j, hp[0], hp[1]);

        __syncthreads();
        if (tid < 256) stage_pollx2(hlds[0], tr + 1024, tid);
        __syncthreads();
        float acc[3][2] = {{0.f,0.f},{0.f,0.f},{0.f,0.f}};
#pragma unroll
        for (int s = 0; s < 2; ++s) {
            const int base = s * 640 + 20 * lane;
#pragma unroll
            for (int c4 = 0; c4 < 4; ++c4) {
                float4 hv = *(const float4*)&hlds[0][base + c4 * 4];
#pragma unroll
                for (int q = 0; q < 3; ++q)
                    acc[q][s] += wh3[q][c4*4+0]*hv.x + wh3[q][c4*4+1]*hv.y
                               + wh3[q][c4*4+2]*hv.z + wh3[q][c4*4+3]*hv.w;
            }
        }
#pragma unroll
        for (int s = 0; s < 2; ++s) {
            float a0 = red32(acc[0][s]), a1 = red32(acc[1][s]), a2 = red32(acc[2][s]);
            hp[s] = gru1(gp[1][s][0], gp[1][s][1], gp[1][s][2], a0, a1, a2, bh2, hp[s]);
        }
        if (lane == 0) pub2(tr + 2048, j, hp[0], hp[1]);
    }

    // ---------- phase E: similarity head (WG 0 only) ----------
    if (wgi != 0) return;
    __syncthreads();
    if (tid < 256) stage_pollx2(xlds[0], tr + 2048, tid);  // [s][512]: hA, hB
    __syncthreads();
    float v = 0.f;
    if (tid < 256) {
        float acc = b_bi[tid];
        for (int jj = 0; jj < 512; ++jj) {
            const float a = xlds[0][LDSP(jj)];
            const float b = xlds[0][LDSP(512 + jj)];
            acc += (a * b) * WA[(size_t)jj * 256 + tid]
                 + fabsf(a - b) * WB[(size_t)jj * 256 + tid];
        }
        v = tanhf(acc) * Wlin[tid];
    }
    v += __shfl_xor(v, 32, 64);
    v += __shfl_xor(v, 16, 64);
    v += __shfl_xor(v, 8, 64);
    v += __shfl_xor(v, 4, 64);
    v += __shfl_xor(v, 2, 64);
    v += __shfl_xor(v, 1, 64);
    if ((tid & 63) == 0) redl[tid >> 6] = v;
    __syncthreads();
    if (tid == 0) {
        float ssum = blin[0];
        for (int i = 0; i < 8; ++i) ssum += redl[i];
        outp[0] = 1.f / (1.f + expf(-ssum));
    }
}

// ---------------------------------------------------------------------------
// init: poison hbuf0/hbuf1 (t=1..256) + tb0/tb1/tr (steps 1..2).
// Re-poison runs every launch (stream-ordered; graph-replay safe).
// ---------------------------------------------------------------------------
__global__ __launch_bounds__(256) void k_init(
    unsigned int* __restrict__ hb0, unsigned int* __restrict__ hb1,
    unsigned int* __restrict__ tb0u, unsigned int* __restrict__ tb1u,
    unsigned int* __restrict__ tru)
{
    const int g = blockIdx.x * 256 + threadIdx.x;
    if (g < 2048) {
        tb0u[1024 + g] = CANARY_U;
        tb1u[1024 + g] = CANARY_U;
        tru[1024 + g]  = CANARY_U;
    }
    const int N = 256 * 1024;                 // words per hbuf, t=1..256
    const int stride = gridDim.x * 256;
    for (int i = g; i < N; i += stride) {
        hb0[1024 + i] = CANARY_U;
        hb1[1024 + i] = CANARY_U;
    }
}

// ---------------------------------------------------------------------------
extern "C" void kernel_launch(void* const* d_in, const int* in_sizes, int n_in,
                              void* d_out, int out_size, void* d_ws, size_t ws_size,
                              hipStream_t stream)
{
    const int*   sentA = (const int*)d_in[0];
    const int*   sentB = (const int*)d_in[1];
    const float* emb   = (const float*)d_in[2];
    const float* Wih1  = (const float*)d_in[3];   // [2][1536][512]
    const float* Whh1  = (const float*)d_in[4];   // [2][1536][512]
    const float* bih1  = (const float*)d_in[5];   // [2][1536]
    const float* bhh1  = (const float*)d_in[6];   // [2][1536]
    const float* convw = (const float*)d_in[7];   // [2][2][512]
    const float* convb = (const float*)d_in[8];   // [2]
    const float* Wih2  = (const float*)d_in[9];   // [1536][128]
    const float* Whh2  = (const float*)d_in[10];  // [1536][512]
    const float* bih2  = (const float*)d_in[11];  // [1536]
    const float* bhh2  = (const float*)d_in[12];  // [1536]
    const float* WA    = (const float*)d_in[13];  // [512][256]
    const float* WB    = (const float*)d_in[14];  // [512][256]
    const float* b_bi  = (const float*)d_in[15];  // [256]
    const float* Wlin  = (const float*)d_in[16];  // [1][256]
    const float* blin  = (const float*)d_in[17];  // [1]

    float* ws = (float*)d_ws;
    size_t off = 0;
    float* hbuf0  = ws + off; off += 257 * 1024;  // [257][512][2]
    float* hbuf1  = ws + off; off += 257 * 1024;  // [257][512][2]
    float* tb0    = ws + off; off += 3 * 1024;    // [3][512][2]
    float* tb1    = ws + off; off += 3 * 1024;
    float* tr     = ws + off; off += 3 * 1024;

    k_init<<<256, 256, 0, stream>>>((unsigned int*)hbuf0, (unsigned int*)hbuf1,
                                    (unsigned int*)tb0, (unsigned int*)tb1,
                                    (unsigned int*)tr);

    k_pipe<<<64, 512, 0, stream>>>(Whh1, bhh1, Wih1, bih1, emb, sentA, sentB,
                                   convw, convb, Whh2, bhh2, bih2, Wih2,
                                   WA, WB, b_bi, Wlin, blin,
                                   hbuf0, hbuf1, tb0, tb1, tr, (float*)d_out);
}